// Round 10
// baseline (585.499 us; speedup 1.0000x reference)
//
#include <hip/hip_runtime.h>

#define NN 100000
#define EE 1600000
#define HH 128
#define GG 64
#define TOT (EE + NN)
#define PSPLIT 8
#define NB 782            // (NN+127)/128 buckets of 128 dst nodes
#define BCAP 4096         // fixed slots per bucket (mean 2046, sigma~45 -> 45 sigma headroom)
#define FCHUNK 4096       // edges per bfill2 block

typedef __attribute__((ext_vector_type(8))) short s16x8;
typedef __attribute__((ext_vector_type(4))) float f32x4;

__device__ __forceinline__ unsigned short f2bf(float f) {
    unsigned u = __float_as_uint(f);
    u = u + 0x7FFFu + ((u >> 16) & 1u);   // round-to-nearest-even
    return (unsigned short)(u >> 16);
}

// ---------------- fused setup: cast + cursor/pool init + bounds(binsearch) + wprep ----------------

__global__ __launch_bounds__(256) void setup_kernel(const float* __restrict__ x,
                                                    const int* __restrict__ batch,
                                                    const float* __restrict__ W0,
                                                    const float* __restrict__ W1,
                                                    const float* __restrict__ W2,
                                                    unsigned* __restrict__ Xbf,
                                                    int* __restrict__ cursor,
                                                    int* __restrict__ gstart, int* __restrict__ gend,
                                                    float* __restrict__ poolsum,
                                                    unsigned short* __restrict__ Wt) {
    int i = blockIdx.x * 256 + threadIdx.x;
    if (i < NN * 64) {                        // cast x -> packed bf16
        float2 v = ((const float2*)x)[i];
        Xbf[i] = (unsigned)f2bf(v.x) | ((unsigned)f2bf(v.y) << 16);
    }
    if (i < NB) cursor[i] = i * BCAP;
    if (i < GG * HH) poolsum[i] = 0.f;
    if (i < GG) {                             // single-writer group bounds via binary search
        // gstart[g] = lower_bound(batch, g); gend[g] = lower_bound(batch, g+1)
        int lo = 0, hi = NN;
        while (lo < hi) { int m = (lo + hi) >> 1; if (batch[m] < i) lo = m + 1; else hi = m; }
        int s = lo;
        lo = 0; hi = NN;
        while (lo < hi) { int m = (lo + hi) >> 1; if (batch[m] < i + 1) lo = m + 1; else hi = m; }
        gstart[i] = s;
        gend[i] = lo;
    }
    if (i < 3 * HH * HH) {                    // W fp32 [k][n] -> bf16 [n][k]
        int l = i >> 14, r = i & 16383;
        const float* W = (l == 0) ? W0 : (l == 1) ? W1 : W2;
        int k = r >> 7, n = r & 127;
        Wt[l * HH * HH + n * HH + k] = f2bf(W[r]);
    }
}

// LDS-aggregated bucket scatter into fixed-capacity regions:
// one global atomic per (block, nonempty bucket); per-edge RMW in LDS; dense write lines.
__global__ __launch_bounds__(256) void bfill2_kernel(const int* __restrict__ ei, int* cursor,
                                                     unsigned* __restrict__ ebuf) {
    __shared__ int h[NB];       // phase1: local count; phase3: local cursor
    __shared__ int lbase[NB];   // reserved global base per bucket
    int tid = threadIdx.x;
    size_t e0 = (size_t)blockIdx.x * FCHUNK;
    for (int i = tid; i < NB; i += 256) h[i] = 0;
    __syncthreads();
    unsigned r[16], c[16];
#pragma unroll
    for (int k = 0; k < 16; ++k) {
        size_t e = e0 + (size_t)k * 256 + tid;
        unsigned rr = 0xFFFFFFFFu, cc = 0;
        if (e < EE) {
            rr = (unsigned)ei[e];
            cc = (unsigned)ei[EE + e];
            if (rr >= NN || cc >= NN) rr = 0xFFFFFFFFu;
        }
        r[k] = rr; c[k] = cc;
        if (rr != 0xFFFFFFFFu) atomicAdd(&h[cc >> 7], 1);
    }
    __syncthreads();
    for (int i = tid; i < NB; i += 256) {
        int cnt = h[i];
        lbase[i] = cnt ? atomicAdd(&cursor[i], cnt) : 0;
    }
    __syncthreads();
    for (int i = tid; i < NB; i += 256) h[i] = 0;
    __syncthreads();
#pragma unroll
    for (int k = 0; k < 16; ++k) {
        if (r[k] != 0xFFFFFFFFu) {
            unsigned cc = c[k];
            int b = cc >> 7;
            int slot = lbase[b] + atomicAdd(&h[b], 1);
            if (slot >= b * BCAP && slot < (b + 1) * BCAP)   // drop on (impossible) overflow
                ebuf[slot] = (r[k] << 7) | (cc & 127u);
        }
    }
}

// scan over buckets: slot offsets only (slots = edges + self-loops); counts from cursor
__global__ void bscan_kernel(const int* __restrict__ cursor, int* __restrict__ bucketSlotStart,
                             int* __restrict__ col_start) {
    __shared__ int ss[1024];
    int t = threadIdx.x;
    int ec = 0, nc = 0;
    if (t < NB) {
        ec = min(max(cursor[t] - t * BCAP, 0), BCAP);
        nc = min(128, NN - t * 128);
    }
    ss[t] = ec + nc;
    __syncthreads();
    for (int off = 1; off < 1024; off <<= 1) {
        int a = 0;
        if (t >= off) a = ss[t - off];
        __syncthreads();
        ss[t] += a;
        __syncthreads();
    }
    if (t < NB) bucketSlotStart[t] = ss[t] - (ec + nc);
    if (t == NB - 1) col_start[NN] = ss[t];
}

// one block per bucket: local count/scan in LDS, emit col_start/dinv/srcv sequentially
__global__ __launch_bounds__(256) void bproc_kernel(const unsigned* __restrict__ ebuf,
                                                    const int* __restrict__ cursor,
                                                    const int* __restrict__ bucketSlotStart,
                                                    int* __restrict__ col_start,
                                                    float* __restrict__ dinv,
                                                    int* __restrict__ srcv) {
    __shared__ unsigned s_e[BCAP];
    __shared__ int s_cnt[128], s_scan[128], s_cur[128];
    int b = blockIdx.x;
    int tid = threadIdx.x;
    int n0 = b * 128;
    int nb = min(128, NN - n0);
    int est = b * BCAP;
    int ecnt = min(max(cursor[b] - est, 0), BCAP);
    if (tid < 128) s_cnt[tid] = 0;
    __syncthreads();
    for (int i = tid; i < ecnt; i += 256) {
        unsigned v = ebuf[est + i];
        s_e[i] = v;
        atomicAdd(&s_cnt[v & 127u], 1);
    }
    __syncthreads();
    int myc = 0;
    if (tid < 128) {
        myc = (tid < nb) ? s_cnt[tid] + 1 : 0;   // +1 self-loop
        s_scan[tid] = myc;
    }
    __syncthreads();
    for (int off = 1; off < 128; off <<= 1) {
        int a = 0;
        if (tid < 128 && tid >= off) a = s_scan[tid - off];
        __syncthreads();
        if (tid < 128) s_scan[tid] += a;
        __syncthreads();
    }
    if (tid < nb) {
        int slotbase = bucketSlotStart[b] + s_scan[tid] - myc;
        col_start[n0 + tid] = slotbase;
        dinv[n0 + tid] = rsqrtf((float)(s_cnt[tid] + 1));
        srcv[slotbase] = n0 + tid;               // self-loop first
        s_cur[tid] = slotbase + 1;
    }
    __syncthreads();
    for (int i = tid; i < ecnt; i += 256) {
        unsigned v = s_e[i];
        int slot = atomicAdd(&s_cur[v & 127u], 1);
        srcv[slot] = (int)(v >> 7);
    }
}

// ---------------- per-layer kernels ----------------

// one wave per dst node; uint4 gathers (16B/lane, 4 rows/issue, 4-pair unroll = 16 rows
// in flight); cross-quarter shfl reduce; bf16 out. Block 0 zeroes BN stats.
__global__ __launch_bounds__(256) void agg_kernel(const uint4* __restrict__ Xbf4,
                                                  const int* __restrict__ col_start,
                                                  const int* __restrict__ srcv,
                                                  const float* __restrict__ dinv,
                                                  unsigned short* __restrict__ Abf,
                                                  float* __restrict__ gsum,
                                                  float* __restrict__ gsq) {
    if (blockIdx.x == 0 && threadIdx.x < HH) {
        gsum[threadIdx.x] = 0.f;
        gsq[threadIdx.x] = 0.f;
    }
    int wid = (int)((blockIdx.x * blockDim.x + threadIdx.x) >> 6);
    int lane = threadIdx.x & 63;
    if (wid >= NN) return;
    int s0 = col_start[wid], s1 = col_start[wid + 1];
    float dd = dinv[wid];
    int q = lane >> 4;        // quarter: which neighbor of the group of 4
    int l16 = lane & 15;      // 16 lanes cover one 256B row (uint4 each)
    float acc[8];
#pragma unroll
    for (int j = 0; j < 8; ++j) acc[j] = 0.f;

    for (int base = s0; base < s1; base += 64) {
        int cnt = min(64, s1 - base);
        int msrc = 0;
        float mw = 0.f;
        if (lane < cnt) { msrc = srcv[base + lane]; mw = dinv[msrc] * dd; }
        int rounds = (cnt + 3) >> 2;
        int p = 0;
        for (; p + 4 <= rounds; p += 4) {
            uint4 u[4];
            float w[4];
#pragma unroll
            for (int k = 0; k < 4; ++k) {
                int idx = (p + k) * 4 + q;
                int src = __shfl(msrc, idx);
                w[k] = __shfl(mw, idx);           // 0 beyond cnt
                u[k] = Xbf4[(size_t)src * 16 + l16];
            }
#pragma unroll
            for (int k = 0; k < 4; ++k) {
                acc[0] += w[k] * __uint_as_float(u[k].x << 16);
                acc[1] += w[k] * __uint_as_float(u[k].x & 0xFFFF0000u);
                acc[2] += w[k] * __uint_as_float(u[k].y << 16);
                acc[3] += w[k] * __uint_as_float(u[k].y & 0xFFFF0000u);
                acc[4] += w[k] * __uint_as_float(u[k].z << 16);
                acc[5] += w[k] * __uint_as_float(u[k].z & 0xFFFF0000u);
                acc[6] += w[k] * __uint_as_float(u[k].w << 16);
                acc[7] += w[k] * __uint_as_float(u[k].w & 0xFFFF0000u);
            }
        }
        for (; p < rounds; ++p) {
            int idx = p * 4 + q;
            int src = __shfl(msrc, idx);
            float w = __shfl(mw, idx);
            uint4 u = Xbf4[(size_t)src * 16 + l16];
            acc[0] += w * __uint_as_float(u.x << 16);
            acc[1] += w * __uint_as_float(u.x & 0xFFFF0000u);
            acc[2] += w * __uint_as_float(u.y << 16);
            acc[3] += w * __uint_as_float(u.y & 0xFFFF0000u);
            acc[4] += w * __uint_as_float(u.z << 16);
            acc[5] += w * __uint_as_float(u.z & 0xFFFF0000u);
            acc[6] += w * __uint_as_float(u.w << 16);
            acc[7] += w * __uint_as_float(u.w & 0xFFFF0000u);
        }
    }
#pragma unroll
    for (int j = 0; j < 8; ++j) {
        acc[j] += __shfl_xor(acc[j], 16);
        acc[j] += __shfl_xor(acc[j], 32);
    }
    if (q == 0) {
        uint4 pk;
        pk.x = (unsigned)f2bf(acc[0]) | ((unsigned)f2bf(acc[1]) << 16);
        pk.y = (unsigned)f2bf(acc[2]) | ((unsigned)f2bf(acc[3]) << 16);
        pk.z = (unsigned)f2bf(acc[4]) | ((unsigned)f2bf(acc[5]) << 16);
        pk.w = (unsigned)f2bf(acc[6]) | ((unsigned)f2bf(acc[7]) << 16);
        ((uint4*)Abf)[(size_t)wid * 16 + l16] = pk;
    }
}

// MFMA pass: BN column sum/sumsq + H stored bf16 IN-PLACE into Abf (each wave
// reads/writes only its own 32 rows; reads complete before epilogue stores).
__global__ __launch_bounds__(256) void gemm_stats_kernel(unsigned short* __restrict__ Abf,
                                                         const unsigned short* __restrict__ Wt,
                                                         const float* __restrict__ bias,
                                                         float* __restrict__ gsum,
                                                         float* __restrict__ gsq) {
    __shared__ unsigned short wlds[128 * 136];   // row stride 136 bf16 = 272B: no b128 conflicts
    __shared__ float ssum[HH], ssq[HH];
    int tid = threadIdx.x;
    if (tid < HH) { ssum[tid] = 0.f; ssq[tid] = 0.f; }
#pragma unroll
    for (int it = 0; it < 16; ++it) {
        int idx = it * 256 + tid;
        int r = idx >> 5, c = idx & 31;
        *(uint2*)&wlds[r * 136 + c * 4] = *(const uint2*)(Wt + r * HH + c * 4);
    }
    __syncthreads();

    int lane = tid & 63;
    int wave = tid >> 6;
    int mcol = lane & 15;
    int quad = lane >> 4;
    int rowbase = blockIdx.x * 128 + wave * 32;
    int row0 = rowbase + mcol;
    int row1 = row0 + 16;

    f32x4 acc[2][8];
#pragma unroll
    for (int mt = 0; mt < 2; ++mt)
#pragma unroll
        for (int nt = 0; nt < 8; ++nt) acc[mt][nt] = (f32x4){0.f, 0.f, 0.f, 0.f};

    s16x8 zf = {0, 0, 0, 0, 0, 0, 0, 0};
#pragma unroll
    for (int ks = 0; ks < 4; ++ks) {
        int k0 = ks * 32 + quad * 8;
        s16x8 a0 = (row0 < NN) ? *(const s16x8*)(Abf + (size_t)row0 * HH + k0) : zf;
        s16x8 a1 = (row1 < NN) ? *(const s16x8*)(Abf + (size_t)row1 * HH + k0) : zf;
#pragma unroll
        for (int nt = 0; nt < 8; ++nt) {
            s16x8 b = *(const s16x8*)&wlds[(nt * 16 + mcol) * 136 + k0];
            acc[0][nt] = __builtin_amdgcn_mfma_f32_16x16x32_bf16(a0, b, acc[0][nt], 0, 0, 0);
            acc[1][nt] = __builtin_amdgcn_mfma_f32_16x16x32_bf16(a1, b, acc[1][nt], 0, 0, 0);
        }
    }

    float s[8], sq[8];
#pragma unroll
    for (int nt = 0; nt < 8; ++nt) { s[nt] = 0.f; sq[nt] = 0.f; }
#pragma unroll
    for (int mt = 0; mt < 2; ++mt) {
        int rbase = rowbase + mt * 16 + quad * 4;
#pragma unroll
        for (int nt = 0; nt < 8; ++nt) {
            int col = nt * 16 + mcol;
            float bv = bias[col];
            f32x4 a = acc[mt][nt];
#pragma unroll
            for (int reg = 0; reg < 4; ++reg) {
                int r = rbase + reg;
                if (r < NN) {
                    float h = a[reg] + bv;
                    Abf[(size_t)r * HH + col] = f2bf(h);   // H (pre-BN) in bf16, in-place
                    s[nt] += h; sq[nt] += h * h;
                }
            }
        }
    }
#pragma unroll
    for (int nt = 0; nt < 8; ++nt) {
        float v = s[nt];  v += __shfl_xor(v, 16);  v += __shfl_xor(v, 32);
        float w = sq[nt]; w += __shfl_xor(w, 16);  w += __shfl_xor(w, 32);
        if (quad == 0) {
            atomicAdd(&ssum[nt * 16 + mcol], v);
            atomicAdd(&ssq[nt * 16 + mcol], w);
        }
    }
    __syncthreads();
    if (tid < HH) {
        atomicAdd(&gsum[tid], ssum[tid]);
        atomicAdd(&gsq[tid], ssq[tid]);
    }
}

// light elementwise: X = relu(asc*H + bsh), bf16 in / bf16 out (H already includes bias)
__global__ __launch_bounds__(256) void apply_kernel(const unsigned short* __restrict__ Hb,
                                                    const float* __restrict__ gsum,
                                                    const float* __restrict__ gsq,
                                                    const float* __restrict__ g,
                                                    const float* __restrict__ beta,
                                                    unsigned short* __restrict__ Xb16) {
    __shared__ float asc[HH], bsh[HH];
    int tid = threadIdx.x;
    if (tid < HH) {
        float mu = gsum[tid] * (1.f / (float)NN);
        float var = fmaxf(gsq[tid] * (1.f / (float)NN) - mu * mu, 0.f);
        float a = g[tid] * rsqrtf(var + 1e-5f);
        asc[tid] = a;
        bsh[tid] = beta[tid] - a * mu;        // o = a*H + (beta - a*mu)
    }
    __syncthreads();
    int i = blockIdx.x * 256 + tid;          // uint4 index: 8 bf16 each
    if (i >= NN * 16) return;
    int c8 = (i & 15) * 8;
    uint4 u = ((const uint4*)Hb)[i];
    unsigned w[4] = {u.x, u.y, u.z, u.w};
    unsigned r[4];
#pragma unroll
    for (int k = 0; k < 4; ++k) {
        int c = c8 + 2 * k;
        float h0 = __uint_as_float(w[k] << 16);
        float h1 = __uint_as_float(w[k] & 0xFFFF0000u);
        float o0 = fmaxf(asc[c] * h0 + bsh[c], 0.f);
        float o1 = fmaxf(asc[c + 1] * h1 + bsh[c + 1], 0.f);
        r[k] = (unsigned)f2bf(o0) | ((unsigned)f2bf(o1) << 16);
    }
    uint4 o;
    o.x = r[0]; o.y = r[1]; o.z = r[2]; o.w = r[3];
    ((uint4*)Xb16)[i] = o;
}

// ---------------- pooling + fc ----------------

__global__ void pool_kernel(const unsigned* __restrict__ Xbf, const int* __restrict__ gstart,
                            const int* __restrict__ gend, float* __restrict__ poolsum) {
    int g = blockIdx.x;
    int sp = blockIdx.y;
    int t = threadIdx.x;           // 64: each handles 2 cols
    int s = gstart[g], e = gend[g];
    if (e <= s) return;
    int len = e - s;
    int chunk = (len + PSPLIT - 1) / PSPLIT;
    int cs = s + sp * chunk;
    int ce = min(cs + chunk, e);
    if (cs >= ce) return;
    float2 acc = make_float2(0.f, 0.f);
    for (int i = cs; i < ce; ++i) {
        unsigned u = Xbf[(size_t)i * 64 + t];
        acc.x += __uint_as_float(u << 16);
        acc.y += __uint_as_float(u & 0xFFFF0000u);
    }
    atomicAdd(&poolsum[g * HH + 2 * t], acc.x);
    atomicAdd(&poolsum[g * HH + 2 * t + 1], acc.y);
}

__global__ void fc_kernel(const float* __restrict__ poolsum, const int* __restrict__ gstart,
                          const int* __restrict__ gend, const float* __restrict__ fc_w,
                          const float* __restrict__ fc_b, float* __restrict__ out) {
    int g = blockIdx.x;
    int o = threadIdx.x;
    int cnt = gend[g] - gstart[g];
    float inv = (cnt > 0) ? (1.f / (float)cnt) : 0.f;
    float acc = fc_b[o];
    for (int k = 0; k < HH; ++k) acc += (poolsum[g * HH + k] * inv) * fc_w[k * HH + o];
    out[g * HH + o] = acc;
}

// ---------------- launch ----------------

extern "C" void kernel_launch(void* const* d_in, const int* in_sizes, int n_in,
                              void* d_out, int out_size, void* d_ws, size_t ws_size,
                              hipStream_t stream) {
    const float* x     = (const float*)d_in[0];
    const int*   ei    = (const int*)d_in[1];
    const int*   batch = (const int*)d_in[2];
    const float* Wl[3]    = {(const float*)d_in[3], (const float*)d_in[7], (const float*)d_in[11]};
    const float* bl[3]    = {(const float*)d_in[4], (const float*)d_in[8], (const float*)d_in[12]};
    const float* gl[3]    = {(const float*)d_in[5], (const float*)d_in[9], (const float*)d_in[13]};
    const float* betal[3] = {(const float*)d_in[6], (const float*)d_in[10], (const float*)d_in[14]};
    const float* fc_w = (const float*)d_in[15];
    const float* fc_b = (const float*)d_in[16];
    float* out = (float*)d_out;

    char* ws = (char*)d_ws;
    size_t off = 0;
    auto take = [&](size_t n) -> void* {
        void* p = ws + off;
        off = (off + n + 255) & ~(size_t)255;
        return p;
    };
    int*   bucketSlotStart = (int*)take((size_t)NB * 4);
    int*   cursor          = (int*)take((size_t)NB * 4);
    unsigned* ebuf         = (unsigned*)take((size_t)NB * BCAP * 4);
    int*   col_start       = (int*)take((size_t)(NN + 1) * 4);
    float* dinv            = (float*)take((size_t)NN * 4);
    int*   srcv            = (int*)take((size_t)TOT * 4);
    float* gsum            = (float*)take(HH * 4);
    float* gsq             = (float*)take(HH * 4);
    int*   gstart          = (int*)take(GG * 4);
    int*   gend            = (int*)take(GG * 4);
    float* poolsum         = (float*)take((size_t)GG * HH * 4);
    unsigned short* wt     = (unsigned short*)take((size_t)3 * HH * HH * 2);
    unsigned* Xbf          = (unsigned*)take((size_t)NN * 64 * 4);
    unsigned short* Abf    = (unsigned short*)take((size_t)NN * HH * 2);

    setup_kernel<<<(NN * 64 + 255) / 256, 256, 0, stream>>>(x, batch, Wl[0], Wl[1], Wl[2],
                                                            Xbf, cursor, gstart, gend, poolsum, wt);
    bfill2_kernel<<<(EE + FCHUNK - 1) / FCHUNK, 256, 0, stream>>>(ei, cursor, ebuf);
    bscan_kernel<<<1, 1024, 0, stream>>>(cursor, bucketSlotStart, col_start);
    bproc_kernel<<<NB, 256, 0, stream>>>(ebuf, cursor, bucketSlotStart, col_start, dinv, srcv);

    for (int l = 0; l < 3; ++l) {
        const unsigned short* W = wt + (size_t)l * HH * HH;
        agg_kernel<<<(NN * 64 + 255) / 256, 256, 0, stream>>>((const uint4*)Xbf, col_start, srcv,
                                                              dinv, Abf, gsum, gsq);
        gemm_stats_kernel<<<(NN + 127) / 128, 256, 0, stream>>>(Abf, W, bl[l], gsum, gsq);
        apply_kernel<<<(NN * 16 + 255) / 256, 256, 0, stream>>>(Abf, gsum, gsq,
                                                                gl[l], betal[l],
                                                                (unsigned short*)Xbf);
    }

    pool_kernel<<<dim3(GG, PSPLIT), 64, 0, stream>>>(Xbf, gstart, gend, poolsum);
    fc_kernel<<<GG, 128, 0, stream>>>(poolsum, gstart, gend, fc_w, fc_b, out);
}

// Round 11
// 555.389 us; speedup vs baseline: 1.0542x; 1.0542x over previous
//
#include <hip/hip_runtime.h>

#define NN 100000
#define EE 1600000
#define HH 128
#define GG 64
#define TOT (EE + NN)
#define PSPLIT 8
#define NB 782            // (NN+127)/128 buckets of 128 dst nodes
#define BCAP 4096         // fixed slots per bucket (mean 2046, sigma~45)
#define FCHUNK 4096       // edges per bfill2 block

typedef __attribute__((ext_vector_type(8))) short s16x8;
typedef __attribute__((ext_vector_type(4))) float f32x4;

__device__ __forceinline__ unsigned short f2bf(float f) {
    unsigned u = __float_as_uint(f);
    u = u + 0x7FFFu + ((u >> 16) & 1u);   // round-to-nearest-even
    return (unsigned short)(u >> 16);
}

// ---------------- fused setup: cast + cursor/pool init + bounds(binsearch) + wprep ----------------

__global__ __launch_bounds__(256) void setup_kernel(const float* __restrict__ x,
                                                    const int* __restrict__ batch,
                                                    const float* __restrict__ W0,
                                                    const float* __restrict__ W1,
                                                    const float* __restrict__ W2,
                                                    unsigned* __restrict__ Xbf,
                                                    int* __restrict__ cursor,
                                                    int* __restrict__ gstart, int* __restrict__ gend,
                                                    float* __restrict__ poolsum,
                                                    unsigned short* __restrict__ Wt) {
    int i = blockIdx.x * 256 + threadIdx.x;
    if (i < NN * 64) {                        // cast x -> packed bf16
        float2 v = ((const float2*)x)[i];
        Xbf[i] = (unsigned)f2bf(v.x) | ((unsigned)f2bf(v.y) << 16);
    }
    if (i < NB) cursor[i] = i * BCAP;
    if (i < GG * HH) poolsum[i] = 0.f;
    if (i < GG) {                             // single-writer group bounds via binary search
        int lo = 0, hi = NN;
        while (lo < hi) { int m = (lo + hi) >> 1; if (batch[m] < i) lo = m + 1; else hi = m; }
        int s = lo;
        lo = 0; hi = NN;
        while (lo < hi) { int m = (lo + hi) >> 1; if (batch[m] < i + 1) lo = m + 1; else hi = m; }
        gstart[i] = s;
        gend[i] = lo;
    }
    if (i < 3 * HH * HH) {                    // W fp32 [k][n] -> bf16 [n][k]
        int l = i >> 14, r = i & 16383;
        const float* W = (l == 0) ? W0 : (l == 1) ? W1 : W2;
        int k = r >> 7, n = r & 127;
        Wt[l * HH * HH + n * HH + k] = f2bf(W[r]);
    }
}

// LDS-aggregated bucket scatter into fixed-capacity regions
__global__ __launch_bounds__(256) void bfill2_kernel(const int* __restrict__ ei, int* cursor,
                                                     unsigned* __restrict__ ebuf) {
    __shared__ int h[NB];
    __shared__ int lbase[NB];
    int tid = threadIdx.x;
    size_t e0 = (size_t)blockIdx.x * FCHUNK;
    for (int i = tid; i < NB; i += 256) h[i] = 0;
    __syncthreads();
    unsigned r[16], c[16];
#pragma unroll
    for (int k = 0; k < 16; ++k) {
        size_t e = e0 + (size_t)k * 256 + tid;
        unsigned rr = 0xFFFFFFFFu, cc = 0;
        if (e < EE) {
            rr = (unsigned)ei[e];
            cc = (unsigned)ei[EE + e];
            if (rr >= NN || cc >= NN) rr = 0xFFFFFFFFu;
        }
        r[k] = rr; c[k] = cc;
        if (rr != 0xFFFFFFFFu) atomicAdd(&h[cc >> 7], 1);
    }
    __syncthreads();
    for (int i = tid; i < NB; i += 256) {
        int cnt = h[i];
        lbase[i] = cnt ? atomicAdd(&cursor[i], cnt) : 0;
    }
    __syncthreads();
    for (int i = tid; i < NB; i += 256) h[i] = 0;
    __syncthreads();
#pragma unroll
    for (int k = 0; k < 16; ++k) {
        if (r[k] != 0xFFFFFFFFu) {
            unsigned cc = c[k];
            int b = cc >> 7;
            int slot = lbase[b] + atomicAdd(&h[b], 1);
            if (slot >= b * BCAP && slot < (b + 1) * BCAP)
                ebuf[slot] = (r[k] << 7) | (cc & 127u);
        }
    }
}

// scan over buckets: slot offsets (slots = edges + self-loops); counts from cursor
__global__ void bscan_kernel(const int* __restrict__ cursor, int* __restrict__ bucketSlotStart,
                             int* __restrict__ col_start) {
    __shared__ int ss[1024];
    int t = threadIdx.x;
    int ec = 0, nc = 0;
    if (t < NB) {
        ec = min(max(cursor[t] - t * BCAP, 0), BCAP);
        nc = min(128, NN - t * 128);
    }
    ss[t] = ec + nc;
    __syncthreads();
    for (int off = 1; off < 1024; off <<= 1) {
        int a = 0;
        if (t >= off) a = ss[t - off];
        __syncthreads();
        ss[t] += a;
        __syncthreads();
    }
    if (t < NB) bucketSlotStart[t] = ss[t] - (ec + nc);
    if (t == NB - 1) col_start[NN] = ss[t];
}

// one block per bucket: local count/scan in LDS, emit col_start/dinv/srcv sequentially
__global__ __launch_bounds__(256) void bproc_kernel(const unsigned* __restrict__ ebuf,
                                                    const int* __restrict__ cursor,
                                                    const int* __restrict__ bucketSlotStart,
                                                    int* __restrict__ col_start,
                                                    float* __restrict__ dinv,
                                                    int* __restrict__ srcv) {
    __shared__ unsigned s_e[BCAP];
    __shared__ int s_cnt[128], s_scan[128], s_cur[128];
    int b = blockIdx.x;
    int tid = threadIdx.x;
    int n0 = b * 128;
    int nb = min(128, NN - n0);
    int est = b * BCAP;
    int ecnt = min(max(cursor[b] - est, 0), BCAP);
    if (tid < 128) s_cnt[tid] = 0;
    __syncthreads();
    for (int i = tid; i < ecnt; i += 256) {
        unsigned v = ebuf[est + i];
        s_e[i] = v;
        atomicAdd(&s_cnt[v & 127u], 1);
    }
    __syncthreads();
    int myc = 0;
    if (tid < 128) {
        myc = (tid < nb) ? s_cnt[tid] + 1 : 0;   // +1 self-loop
        s_scan[tid] = myc;
    }
    __syncthreads();
    for (int off = 1; off < 128; off <<= 1) {
        int a = 0;
        if (tid < 128 && tid >= off) a = s_scan[tid - off];
        __syncthreads();
        if (tid < 128) s_scan[tid] += a;
        __syncthreads();
    }
    if (tid < nb) {
        int slotbase = bucketSlotStart[b] + s_scan[tid] - myc;
        col_start[n0 + tid] = slotbase;
        dinv[n0 + tid] = rsqrtf((float)(s_cnt[tid] + 1));
        srcv[slotbase] = n0 + tid;               // self-loop first
        s_cur[tid] = slotbase + 1;
    }
    __syncthreads();
    for (int i = tid; i < ecnt; i += 256) {
        unsigned v = s_e[i];
        int slot = atomicAdd(&s_cur[v & 127u], 1);
        srcv[slot] = (int)(v >> 7);
    }
}

// ---------------- per-layer kernels ----------------

// TWO dst nodes per wave (lanes 0-31 -> node 2w, lanes 32-63 -> node 2w+1).
// Per half: 2 quarters of 16 lanes; rounds = ceil(cnt/2) ~9 at mean degree 17,
// so the u[6] batch actually fills -> 6 load-instrs in flight per wave (was 4).
__global__ __launch_bounds__(256) void agg_kernel(const uint4* __restrict__ Xbf4,
                                                  const int* __restrict__ col_start,
                                                  const int* __restrict__ srcv,
                                                  const float* __restrict__ dinv,
                                                  unsigned short* __restrict__ Abf,
                                                  float* __restrict__ gsum,
                                                  float* __restrict__ gsq) {
    if (blockIdx.x == 0 && threadIdx.x < HH) {
        gsum[threadIdx.x] = 0.f;
        gsq[threadIdx.x] = 0.f;
    }
    int wv = (int)((blockIdx.x * blockDim.x + threadIdx.x) >> 6);
    int lane = threadIdx.x & 63;
    int half = lane >> 5;
    int node = 2 * wv + half;
    if (2 * wv >= NN) return;
    bool valid = node < NN;
    int s0 = 0, s1 = 0;
    float dd = 0.f;
    if (valid) { s0 = col_start[node]; s1 = col_start[node + 1]; dd = dinv[node]; }
    int lane31 = lane & 31;
    int qh = (lane >> 4) & 1;     // quarter within half
    int l16 = lane & 15;          // 16 lanes cover one 256B row (uint4 each)
    float acc[8];
#pragma unroll
    for (int j = 0; j < 8; ++j) acc[j] = 0.f;

    for (int base = s0; base < s1; base += 32) {
        int cnt = min(32, s1 - base);
        int msrc = 0;
        float mw = 0.f;
        if (lane31 < cnt) { msrc = srcv[base + lane31]; mw = dinv[msrc] * dd; }
        int rounds = (cnt + 1) >> 1;
        int p = 0;
        for (; p + 6 <= rounds; p += 6) {
            uint4 u[6];
            float w[6];
#pragma unroll
            for (int k = 0; k < 6; ++k) {
                int sl = half * 32 + (p + k) * 2 + qh;   // <= 31 within half
                int src = __shfl(msrc, sl);
                w[k] = __shfl(mw, sl);                   // 0 beyond cnt (preload zeroed)
                u[k] = Xbf4[(size_t)src * 16 + l16];
            }
#pragma unroll
            for (int k = 0; k < 6; ++k) {
                acc[0] += w[k] * __uint_as_float(u[k].x << 16);
                acc[1] += w[k] * __uint_as_float(u[k].x & 0xFFFF0000u);
                acc[2] += w[k] * __uint_as_float(u[k].y << 16);
                acc[3] += w[k] * __uint_as_float(u[k].y & 0xFFFF0000u);
                acc[4] += w[k] * __uint_as_float(u[k].z << 16);
                acc[5] += w[k] * __uint_as_float(u[k].z & 0xFFFF0000u);
                acc[6] += w[k] * __uint_as_float(u[k].w << 16);
                acc[7] += w[k] * __uint_as_float(u[k].w & 0xFFFF0000u);
            }
        }
        for (; p < rounds; ++p) {
            int sl = half * 32 + p * 2 + qh;
            int src = __shfl(msrc, sl);
            float w = __shfl(mw, sl);
            uint4 u = Xbf4[(size_t)src * 16 + l16];
            acc[0] += w * __uint_as_float(u.x << 16);
            acc[1] += w * __uint_as_float(u.x & 0xFFFF0000u);
            acc[2] += w * __uint_as_float(u.y << 16);
            acc[3] += w * __uint_as_float(u.y & 0xFFFF0000u);
            acc[4] += w * __uint_as_float(u.z << 16);
            acc[5] += w * __uint_as_float(u.z & 0xFFFF0000u);
            acc[6] += w * __uint_as_float(u.w << 16);
            acc[7] += w * __uint_as_float(u.w & 0xFFFF0000u);
        }
    }
#pragma unroll
    for (int j = 0; j < 8; ++j) acc[j] += __shfl_xor(acc[j], 16);   // combine the 2 quarters
    if ((lane & 16) == 0 && valid) {
        uint4 pk;
        pk.x = (unsigned)f2bf(acc[0]) | ((unsigned)f2bf(acc[1]) << 16);
        pk.y = (unsigned)f2bf(acc[2]) | ((unsigned)f2bf(acc[3]) << 16);
        pk.z = (unsigned)f2bf(acc[4]) | ((unsigned)f2bf(acc[5]) << 16);
        pk.w = (unsigned)f2bf(acc[6]) | ((unsigned)f2bf(acc[7]) << 16);
        ((uint4*)Abf)[(size_t)node * 16 + l16] = pk;
    }
}

// pass 1: MFMA product, BN column sum/sumsq only — H never materialized (R8 structure).
__global__ __launch_bounds__(256) void gemm_stats_kernel(const unsigned short* __restrict__ Abf,
                                                         const unsigned short* __restrict__ Wt,
                                                         const float* __restrict__ bias,
                                                         float* __restrict__ gsum,
                                                         float* __restrict__ gsq) {
    __shared__ unsigned short wlds[128 * 136];   // row stride 136 bf16 = 272B: no b128 conflicts
    __shared__ float ssum[HH], ssq[HH];
    int tid = threadIdx.x;
    if (tid < HH) { ssum[tid] = 0.f; ssq[tid] = 0.f; }
#pragma unroll
    for (int it = 0; it < 16; ++it) {
        int idx = it * 256 + tid;
        int r = idx >> 5, c = idx & 31;
        *(uint2*)&wlds[r * 136 + c * 4] = *(const uint2*)(Wt + r * HH + c * 4);
    }
    __syncthreads();

    int lane = tid & 63;
    int wave = tid >> 6;
    int mcol = lane & 15;
    int quad = lane >> 4;
    int rowbase = blockIdx.x * 128 + wave * 32;
    int row0 = rowbase + mcol;
    int row1 = row0 + 16;

    f32x4 acc[2][8];
#pragma unroll
    for (int mt = 0; mt < 2; ++mt)
#pragma unroll
        for (int nt = 0; nt < 8; ++nt) acc[mt][nt] = (f32x4){0.f, 0.f, 0.f, 0.f};

    s16x8 zf = {0, 0, 0, 0, 0, 0, 0, 0};
#pragma unroll
    for (int ks = 0; ks < 4; ++ks) {
        int k0 = ks * 32 + quad * 8;
        s16x8 a0 = (row0 < NN) ? *(const s16x8*)(Abf + (size_t)row0 * HH + k0) : zf;
        s16x8 a1 = (row1 < NN) ? *(const s16x8*)(Abf + (size_t)row1 * HH + k0) : zf;
#pragma unroll
        for (int nt = 0; nt < 8; ++nt) {
            s16x8 b = *(const s16x8*)&wlds[(nt * 16 + mcol) * 136 + k0];
            acc[0][nt] = __builtin_amdgcn_mfma_f32_16x16x32_bf16(a0, b, acc[0][nt], 0, 0, 0);
            acc[1][nt] = __builtin_amdgcn_mfma_f32_16x16x32_bf16(a1, b, acc[1][nt], 0, 0, 0);
        }
    }

    float s[8], sq[8];
#pragma unroll
    for (int nt = 0; nt < 8; ++nt) { s[nt] = 0.f; sq[nt] = 0.f; }
#pragma unroll
    for (int mt = 0; mt < 2; ++mt) {
        int rbase = rowbase + mt * 16 + quad * 4;
#pragma unroll
        for (int nt = 0; nt < 8; ++nt) {
            float bv = bias[nt * 16 + mcol];
            f32x4 a = acc[mt][nt];
#pragma unroll
            for (int reg = 0; reg < 4; ++reg) {
                if (rbase + reg < NN) {
                    float h = a[reg] + bv;
                    s[nt] += h; sq[nt] += h * h;
                }
            }
        }
    }
#pragma unroll
    for (int nt = 0; nt < 8; ++nt) {
        float v = s[nt];  v += __shfl_xor(v, 16);  v += __shfl_xor(v, 32);
        float w = sq[nt]; w += __shfl_xor(w, 16);  w += __shfl_xor(w, 32);
        if (quad == 0) {
            atomicAdd(&ssum[nt * 16 + mcol], v);
            atomicAdd(&ssq[nt * 16 + mcol], w);
        }
    }
    __syncthreads();
    if (tid < HH) {
        atomicAdd(&gsum[tid], ssum[tid]);
        atomicAdd(&gsq[tid], ssq[tid]);
    }
}

// pass 2: recompute MFMA product, apply bias+BN+ReLU, store bf16 X (R8 structure).
__global__ __launch_bounds__(256) void gemm_apply_kernel(const unsigned short* __restrict__ Abf,
                                                         const unsigned short* __restrict__ Wt,
                                                         const float* __restrict__ bias,
                                                         const float* __restrict__ gsum,
                                                         const float* __restrict__ gsq,
                                                         const float* __restrict__ g,
                                                         const float* __restrict__ beta,
                                                         unsigned short* __restrict__ Xb16) {
    __shared__ unsigned short wlds[128 * 136];
    __shared__ float asc[HH], bsh[HH];
    int tid = threadIdx.x;
#pragma unroll
    for (int it = 0; it < 16; ++it) {
        int idx = it * 256 + tid;
        int r = idx >> 5, c = idx & 31;
        *(uint2*)&wlds[r * 136 + c * 4] = *(const uint2*)(Wt + r * HH + c * 4);
    }
    if (tid < HH) {
        float mu = gsum[tid] * (1.f / (float)NN);
        float var = fmaxf(gsq[tid] * (1.f / (float)NN) - mu * mu, 0.f);
        float a = g[tid] * rsqrtf(var + 1e-5f);
        asc[tid] = a;
        bsh[tid] = a * (bias[tid] - mu) + beta[tid];   // o = a*acc + bsh (acc pre-bias)
    }
    __syncthreads();

    int lane = tid & 63;
    int wave = tid >> 6;
    int mcol = lane & 15;
    int quad = lane >> 4;
    int rowbase = blockIdx.x * 128 + wave * 32;
    int row0 = rowbase + mcol;
    int row1 = row0 + 16;

    f32x4 acc[2][8];
#pragma unroll
    for (int mt = 0; mt < 2; ++mt)
#pragma unroll
        for (int nt = 0; nt < 8; ++nt) acc[mt][nt] = (f32x4){0.f, 0.f, 0.f, 0.f};

    s16x8 zf = {0, 0, 0, 0, 0, 0, 0, 0};
#pragma unroll
    for (int ks = 0; ks < 4; ++ks) {
        int k0 = ks * 32 + quad * 8;
        s16x8 a0 = (row0 < NN) ? *(const s16x8*)(Abf + (size_t)row0 * HH + k0) : zf;
        s16x8 a1 = (row1 < NN) ? *(const s16x8*)(Abf + (size_t)row1 * HH + k0) : zf;
#pragma unroll
        for (int nt = 0; nt < 8; ++nt) {
            s16x8 b = *(const s16x8*)&wlds[(nt * 16 + mcol) * 136 + k0];
            acc[0][nt] = __builtin_amdgcn_mfma_f32_16x16x32_bf16(a0, b, acc[0][nt], 0, 0, 0);
            acc[1][nt] = __builtin_amdgcn_mfma_f32_16x16x32_bf16(a1, b, acc[1][nt], 0, 0, 0);
        }
    }

#pragma unroll
    for (int mt = 0; mt < 2; ++mt) {
        int rbase = rowbase + mt * 16 + quad * 4;
#pragma unroll
        for (int nt = 0; nt < 8; ++nt) {
            int col = nt * 16 + mcol;
            float av = asc[col], bv = bsh[col];
            f32x4 a = acc[mt][nt];
#pragma unroll
            for (int reg = 0; reg < 4; ++reg) {
                int r = rbase + reg;
                if (r < NN) {
                    float o = fmaxf(av * a[reg] + bv, 0.f);
                    Xb16[(size_t)r * HH + col] = f2bf(o);
                }
            }
        }
    }
}

// ---------------- pooling + fc ----------------

__global__ void pool_kernel(const unsigned* __restrict__ Xbf, const int* __restrict__ gstart,
                            const int* __restrict__ gend, float* __restrict__ poolsum) {
    int g = blockIdx.x;
    int sp = blockIdx.y;
    int t = threadIdx.x;           // 64: each handles 2 cols
    int s = gstart[g], e = gend[g];
    if (e <= s) return;
    int len = e - s;
    int chunk = (len + PSPLIT - 1) / PSPLIT;
    int cs = s + sp * chunk;
    int ce = min(cs + chunk, e);
    if (cs >= ce) return;
    float2 acc = make_float2(0.f, 0.f);
    for (int i = cs; i < ce; ++i) {
        unsigned u = Xbf[(size_t)i * 64 + t];
        acc.x += __uint_as_float(u << 16);
        acc.y += __uint_as_float(u & 0xFFFF0000u);
    }
    atomicAdd(&poolsum[g * HH + 2 * t], acc.x);
    atomicAdd(&poolsum[g * HH + 2 * t + 1], acc.y);
}

__global__ void fc_kernel(const float* __restrict__ poolsum, const int* __restrict__ gstart,
                          const int* __restrict__ gend, const float* __restrict__ fc_w,
                          const float* __restrict__ fc_b, float* __restrict__ out) {
    int g = blockIdx.x;
    int o = threadIdx.x;
    int cnt = gend[g] - gstart[g];
    float inv = (cnt > 0) ? (1.f / (float)cnt) : 0.f;
    float acc = fc_b[o];
    for (int k = 0; k < HH; ++k) acc += (poolsum[g * HH + k] * inv) * fc_w[k * HH + o];
    out[g * HH + o] = acc;
}

// ---------------- launch ----------------

extern "C" void kernel_launch(void* const* d_in, const int* in_sizes, int n_in,
                              void* d_out, int out_size, void* d_ws, size_t ws_size,
                              hipStream_t stream) {
    const float* x     = (const float*)d_in[0];
    const int*   ei    = (const int*)d_in[1];
    const int*   batch = (const int*)d_in[2];
    const float* Wl[3]    = {(const float*)d_in[3], (const float*)d_in[7], (const float*)d_in[11]};
    const float* bl[3]    = {(const float*)d_in[4], (const float*)d_in[8], (const float*)d_in[12]};
    const float* gl[3]    = {(const float*)d_in[5], (const float*)d_in[9], (const float*)d_in[13]};
    const float* betal[3] = {(const float*)d_in[6], (const float*)d_in[10], (const float*)d_in[14]};
    const float* fc_w = (const float*)d_in[15];
    const float* fc_b = (const float*)d_in[16];
    float* out = (float*)d_out;

    char* ws = (char*)d_ws;
    size_t off = 0;
    auto take = [&](size_t n) -> void* {
        void* p = ws + off;
        off = (off + n + 255) & ~(size_t)255;
        return p;
    };
    int*   bucketSlotStart = (int*)take((size_t)NB * 4);
    int*   cursor          = (int*)take((size_t)NB * 4);
    unsigned* ebuf         = (unsigned*)take((size_t)NB * BCAP * 4);
    int*   col_start       = (int*)take((size_t)(NN + 1) * 4);
    float* dinv            = (float*)take((size_t)NN * 4);
    int*   srcv            = (int*)take((size_t)TOT * 4);
    float* gsum            = (float*)take(HH * 4);
    float* gsq             = (float*)take(HH * 4);
    int*   gstart          = (int*)take(GG * 4);
    int*   gend            = (int*)take(GG * 4);
    float* poolsum         = (float*)take((size_t)GG * HH * 4);
    unsigned short* wt     = (unsigned short*)take((size_t)3 * HH * HH * 2);
    unsigned* Xbf          = (unsigned*)take((size_t)NN * 64 * 4);
    unsigned short* Abf    = (unsigned short*)take((size_t)NN * HH * 2);

    setup_kernel<<<(NN * 64 + 255) / 256, 256, 0, stream>>>(x, batch, Wl[0], Wl[1], Wl[2],
                                                            Xbf, cursor, gstart, gend, poolsum, wt);
    bfill2_kernel<<<(EE + FCHUNK - 1) / FCHUNK, 256, 0, stream>>>(ei, cursor, ebuf);
    bscan_kernel<<<1, 1024, 0, stream>>>(cursor, bucketSlotStart, col_start);
    bproc_kernel<<<NB, 256, 0, stream>>>(ebuf, cursor, bucketSlotStart, col_start, dinv, srcv);

    const int aggBlocks = (((NN + 1) / 2) * 64 + 255) / 256;   // 2 nodes per wave
    for (int l = 0; l < 3; ++l) {
        const unsigned short* W = wt + (size_t)l * HH * HH;
        agg_kernel<<<aggBlocks, 256, 0, stream>>>((const uint4*)Xbf, col_start, srcv,
                                                  dinv, Abf, gsum, gsq);
        gemm_stats_kernel<<<(NN + 127) / 128, 256, 0, stream>>>(Abf, W, bl[l], gsum, gsq);
        gemm_apply_kernel<<<(NN + 127) / 128, 256, 0, stream>>>(Abf, W, bl[l], gsum, gsq,
                                                                gl[l], betal[l],
                                                                (unsigned short*)Xbf);
    }

    pool_kernel<<<dim3(GG, PSPLIT), 64, 0, stream>>>(Xbf, gstart, gend, poolsum);
    fc_kernel<<<GG, 128, 0, stream>>>(poolsum, gstart, gend, fc_w, fc_b, out);
}